// Round 1
// baseline (520.162 us; speedup 1.0000x reference)
//
#include <hip/hip_runtime.h>
#include <hip/hip_bf16.h>
#include <math.h>

typedef float f32x4 __attribute__((ext_vector_type(4)));
typedef __bf16 bf16x8 __attribute__((ext_vector_type(8)));

constexpr int B   = 8192;
constexpr int HID = 512;
constexpr int R   = 16;
constexpr int K   = 512;
constexpr int NC  = 16;
constexpr int KK  = R * K;     // 8192 contraction length
constexpr int BM  = 128, BN = 128, BK = 64;
constexpr int NT  = KK / BK;   // 128 K-steps

// pack two fp32 -> two bf16 (round-half-up via +0x8000, then byte-perm pack)
__device__ inline unsigned pack_bf16(float a, float b) {
  unsigned ua = __builtin_bit_cast(unsigned, a) + 0x8000u;
  unsigned ub = __builtin_bit_cast(unsigned, b) + 0x8000u;
  // result bytes (LSB..): {ua.b2, ua.b3, ub.b2, ub.b3}; idx0-3=src1, idx4-7=src0
  return __builtin_amdgcn_perm(ub, ua, 0x07060302u);
}

// XOR swizzle inside a [row][64 bf16] (=128B) tile row; byte granularity 16B slots
__device__ inline int swz(int row, int colbyte) {
  return row * 128 + (colbyte ^ ((row & 7) << 4));
}

// ---------------- kernel 0: W[h][r][k] -> bf16 Wt[h][k*16+r] ----------------
__global__ void wconv_kernel(const float* __restrict__ W, ushort* __restrict__ Wt) {
  int t = blockIdx.x * blockDim.x + threadIdx.x;  // [0, HID*K)
  int h = t >> 9, k = t & (K - 1);
  const float* src = W + (size_t)h * KK + k;      // stride K between r's
  unsigned pk[8];
#pragma unroll
  for (int rp = 0; rp < 8; ++rp) {
    float a = src[(size_t)(2 * rp) * K];
    float b = src[(size_t)(2 * rp + 1) * K];
    pk[rp] = pack_bf16(a, b);
  }
  uint4* dst = reinterpret_cast<uint4*>(Wt + (size_t)h * KK + k * R);
  dst[0] = make_uint4(pk[0], pk[1], pk[2], pk[3]);
  dst[1] = make_uint4(pk[4], pk[5], pk[6], pk[7]);
}

// ---------------- kernel 1: s = x @ Wt^T, h = tanh(s) ----------------
// A = x [B][KK] fp32 (converted to bf16 on the fly), Bmat = Wt [HID][KK] bf16.
__global__ __launch_bounds__(512, 1)
void gemm_tanh_kernel(const float* __restrict__ x, const ushort* __restrict__ Wt,
                      float* __restrict__ hout) {
  __shared__ ushort ldsA[2][BM * BK];  // 16 KB each, swizzled rows of 64 bf16
  __shared__ ushort ldsB[2][BN * BK];

  // XCD-grouped mapping: XCD x gets m-panels x*8..x*8+7, its 4 n-tiles adjacent
  int bid = blockIdx.x;
  int xcd = bid & 7, j = bid >> 3;
  int mt = xcd * 8 + (j >> 2), ntile = j & 3;
  int m_base = mt * BM, n_base = ntile * BN;

  int t = threadIdx.x;
  int lane = t & 63, wid = t >> 6;
  int wm = wid >> 2, wn = wid & 3;  // 2 x 4 wave grid, wave tile 64(M) x 32(N)

  const float*  xg = x  + (size_t)m_base * KK;
  const ushort* wg = Wt + (size_t)n_base * KK;

  f32x4 areg[4];
  uint4 breg[2];

  auto loadTile = [&](int kt) {
    int koff = kt * BK;
#pragma unroll
    for (int p = 0; p < 4; ++p) {        // 128x64 fp32: 2048 f4, 4 per thread
      int g = t + p * 512;
      int row = g >> 4, col = (g & 15) * 4;
      areg[p] = *reinterpret_cast<const f32x4*>(xg + (size_t)row * KK + koff + col);
    }
#pragma unroll
    for (int p = 0; p < 2; ++p) {        // 128x64 bf16: 1024 x 16B, 2 per thread
      int g = t + p * 512;
      int row = g >> 3, col = (g & 7) * 8;
      breg[p] = *reinterpret_cast<const uint4*>(wg + (size_t)row * KK + koff + col);
    }
  };

  auto writeTile = [&](int buf) {
    char* baseA = reinterpret_cast<char*>(ldsA[buf]);
    char* baseB = reinterpret_cast<char*>(ldsB[buf]);
#pragma unroll
    for (int p = 0; p < 4; ++p) {
      int g = t + p * 512;
      int row = g >> 4, colb = (g & 15) * 8;   // 4 bf16 = 8 bytes
      unsigned lo = pack_bf16(areg[p].x, areg[p].y);
      unsigned hi = pack_bf16(areg[p].z, areg[p].w);
      *reinterpret_cast<uint2*>(baseA + swz(row, colb)) = make_uint2(lo, hi);
    }
#pragma unroll
    for (int p = 0; p < 2; ++p) {
      int g = t + p * 512;
      int row = g >> 3, colb = (g & 7) * 16;
      *reinterpret_cast<uint4*>(baseB + swz(row, colb)) = breg[p];
    }
  };

  f32x4 acc[4][2] = {};

  loadTile(0);
  writeTile(0);
  __syncthreads();
  loadTile(1);

  int cur = 0;
  for (int tt = 0; tt < NT; ++tt) {
    if (tt + 1 < NT) {
      writeTile(cur ^ 1);                 // waits vmcnt for loads issued last iter
      if (tt + 2 < NT) loadTile(tt + 2);  // issue next loads early
    }
    const char* baseA = reinterpret_cast<const char*>(ldsA[cur]);
    const char* baseB = reinterpret_cast<const char*>(ldsB[cur]);
#pragma unroll
    for (int kk = 0; kk < 2; ++kk) {
      int kb = kk * 64 + (lane >> 4) * 16;  // byte offset of this lane's 8 k-elems
      bf16x8 af[4], bfr[2];
#pragma unroll
      for (int m = 0; m < 4; ++m) {
        int row = wm * 64 + m * 16 + (lane & 15);
        af[m] = *reinterpret_cast<const bf16x8*>(baseA + swz(row, kb));
      }
#pragma unroll
      for (int n = 0; n < 2; ++n) {
        int row = wn * 32 + n * 16 + (lane & 15);
        bfr[n] = *reinterpret_cast<const bf16x8*>(baseB + swz(row, kb));
      }
#pragma unroll
      for (int m = 0; m < 4; ++m)
#pragma unroll
        for (int n = 0; n < 2; ++n)
          acc[m][n] = __builtin_amdgcn_mfma_f32_16x16x32_bf16(af[m], bfr[n], acc[m][n], 0, 0, 0);
    }
    __syncthreads();
    cur ^= 1;
  }

  // epilogue: tanh -> hout[b][h] fp32.  C layout: col=lane&15, row=(lane>>4)*4+j
#pragma unroll
  for (int m = 0; m < 4; ++m) {
    int row0 = m_base + wm * 64 + m * 16 + (lane >> 4) * 4;
#pragma unroll
    for (int n = 0; n < 2; ++n) {
      int col = n_base + wn * 32 + n * 16 + (lane & 15);
#pragma unroll
      for (int jj = 0; jj < 4; ++jj)
        hout[(size_t)(row0 + jj) * HID + col] = tanhf(acc[m][n][jj]);
    }
  }
}

// ---------------- kernel 2: out = h @ V^T + b ----------------
__global__ __launch_bounds__(256)
void proj_kernel(const float* __restrict__ hbuf, const float* __restrict__ V,
                 const float* __restrict__ bias, float* __restrict__ out) {
  __shared__ float Vs[NC * HID];  // 32 KB
  int t = threadIdx.x;
#pragma unroll
  for (int p = 0; p < 8; ++p) {   // 2048 f4 / 256 threads
    int g = t + p * 256;
    reinterpret_cast<f32x4*>(Vs)[g] = reinterpret_cast<const f32x4*>(V)[g];
  }
  __syncthreads();
  int wid = t >> 6, lane = t & 63;
  int brow = blockIdx.x * 4 + wid;
  const float* hr = hbuf + (size_t)brow * HID;
  float hv[8];
#pragma unroll
  for (int jj = 0; jj < 8; ++jj) hv[jj] = hr[jj * 64 + lane];  // coalesced, stride-64 per lane
  float acc[NC];
#pragma unroll
  for (int c = 0; c < NC; ++c) acc[c] = 0.f;
#pragma unroll
  for (int jj = 0; jj < 8; ++jj)
#pragma unroll
    for (int c = 0; c < NC; ++c)
      acc[c] += hv[jj] * Vs[c * HID + jj * 64 + lane];  // lane-consecutive: conflict-free
  float myval = 0.f;
#pragma unroll
  for (int c = 0; c < NC; ++c) {
    float s = acc[c];
#pragma unroll
    for (int off = 32; off > 0; off >>= 1) s += __shfl_xor(s, off);
    if (lane == c) myval = s;
  }
  if (lane < NC) out[(size_t)brow * NC + lane] = myval + bias[lane];
}

extern "C" void kernel_launch(void* const* d_in, const int* in_sizes, int n_in,
                              void* d_out, int out_size, void* d_ws, size_t ws_size,
                              hipStream_t stream) {
  const float* x = (const float*)d_in[0];
  const float* W = (const float*)d_in[1];
  const float* V = (const float*)d_in[2];
  const float* b = (const float*)d_in[3];
  float* out = (float*)d_out;

  ushort* Wt   = (ushort*)d_ws;                                        // 8 MB
  float*  hbuf = (float*)((char*)d_ws + (size_t)HID * KK * sizeof(ushort));  // 16 MB

  wconv_kernel<<<HID * K / 256, 256, 0, stream>>>(W, Wt);
  gemm_tanh_kernel<<<(B / BM) * (HID / BN), 512, 0, stream>>>(x, Wt, hbuf);
  proj_kernel<<<B / 4, 256, 0, stream>>>(hbuf, V, b, out);
}

// Round 5
// 450.403 us; speedup vs baseline: 1.1549x; 1.1549x over previous
//
#include <hip/hip_runtime.h>
#include <hip/hip_bf16.h>
#include <math.h>

typedef float f32x4 __attribute__((ext_vector_type(4)));
typedef __bf16 bf16x8 __attribute__((ext_vector_type(8)));

#define GLOBAL_AS __attribute__((address_space(1)))
#define LDS_AS    __attribute__((address_space(3)))

constexpr int B   = 8192;
constexpr int HID = 512;
constexpr int R   = 16;
constexpr int K   = 512;
constexpr int NC  = 16;
constexpr int KK  = R * K;       // 8192 contraction length
constexpr int BM  = 128, BN = 128, BK = 64;
constexpr int KSPLIT = 2;
constexpr int KS  = KK / KSPLIT; // 4096 per K-chunk
constexpr int NTK = KS / BK;     // 64 K-steps per block

// pack two fp32 -> two bf16 (round-half-up via +0x8000, then byte-perm pack)
__device__ inline unsigned pack_bf16(float a, float b) {
  unsigned ua = __builtin_bit_cast(unsigned, a) + 0x8000u;
  unsigned ub = __builtin_bit_cast(unsigned, b) + 0x8000u;
  return __builtin_amdgcn_perm(ub, ua, 0x07060302u);
}

// XOR swizzle inside a [row][64 bf16] (=128B) tile row
__device__ inline int swz(int row, int colbyte) {
  return row * 128 + (colbyte ^ ((row & 7) << 4));
}

// ---------------- kernel 0: W[h][r][k] -> bf16 Wt[h][k*16+r] ----------------
__global__ void wconv_kernel(const float* __restrict__ W, ushort* __restrict__ Wt) {
  int t = blockIdx.x * blockDim.x + threadIdx.x;  // [0, HID*K)
  int h = t >> 9, k = t & (K - 1);
  const float* src = W + (size_t)h * KK + k;      // stride K between r's
  unsigned pk[8];
#pragma unroll
  for (int rp = 0; rp < 8; ++rp) {
    float a = src[(size_t)(2 * rp) * K];
    float b = src[(size_t)(2 * rp + 1) * K];
    pk[rp] = pack_bf16(a, b);
  }
  uint4* dst = reinterpret_cast<uint4*>(Wt + (size_t)h * KK + k * R);
  dst[0] = make_uint4(pk[0], pk[1], pk[2], pk[3]);
  dst[1] = make_uint4(pk[4], pk[5], pk[6], pk[7]);
}

// ---------------- kernel 1: split-K GEMM, partial[kc] = x_chunk @ Wt_chunk^T ----------------
__global__ __launch_bounds__(512, 4)
void gemm_splitk_kernel(const float* __restrict__ x, const ushort* __restrict__ Wt,
                        float* __restrict__ part) {
  __shared__ ushort ldsA[2][BM * BK];  // 16 KB each
  __shared__ ushort ldsB[2][BN * BK];  // 16 KB each  (total 64 KB -> 2 blocks/CU)

  // XCD-grouped mapping: 8 M-panels per XCD; same-panel blocks adjacent
  int bid = blockIdx.x;
  int xcd = bid & 7, j = bid >> 3;           // j in [0,64)
  int mt = xcd * 8 + (j >> 3);               // 64 M-tiles
  int kc = (j >> 2) & 1, nt = j & 3;         // 2 K-chunks x 4 N-tiles
  int m_base = mt * BM, n_base = nt * BN;

  int t = threadIdx.x;
  int lane = t & 63, wid = t >> 6;
  int wm = wid >> 2, wn = wid & 3;           // 2x4 wave grid, wave tile 64(M) x 32(N)

  const float* xg = x + (size_t)m_base * KK + (size_t)kc * KS;
  const char*  bg = (const char*)(Wt + (size_t)n_base * KK + (size_t)kc * KS);
  float* pout = part + (size_t)kc * B * HID;

  f32x4 areg[4];

  auto loadA = [&](int tt) {
    int koff = tt * BK;
#pragma unroll
    for (int p = 0; p < 4; ++p) {            // 128x64 fp32: 4 f32x4 per thread
      int g = t + p * 512;
      int row = g >> 4, col = (g & 15) * 4;
      areg[p] = *reinterpret_cast<const f32x4*>(xg + (size_t)row * KK + koff + col);
    }
  };

  auto writeA = [&](int buf) {
    char* baseA = reinterpret_cast<char*>(ldsA[buf]);
#pragma unroll
    for (int p = 0; p < 4; ++p) {
      int g = t + p * 512;
      int row = g >> 4, colb = (g & 15) * 8;
      unsigned lo = pack_bf16(areg[p].x, areg[p].y);
      unsigned hi = pack_bf16(areg[p].z, areg[p].w);
      *reinterpret_cast<uint2*>(baseA + swz(row, colb)) = make_uint2(lo, hi);
    }
  };

  // B: async global->LDS, linear LDS dest + inverse-swizzled global source
  auto gldB = [&](int buf, int tt) {
    char* lb = reinterpret_cast<char*>(ldsB[buf]);
#pragma unroll
    for (int p = 0; p < 2; ++p) {            // 16 KB tile = 2 rounds x 8 waves x 1 KB
      int chunk = p * 8 + wid;               // wave-uniform
      int o = chunk * 1024 + lane * 16;      // linear LDS byte slot
      int r = o >> 7, cb = o & 127;
      size_t soff = (size_t)r * (KK * 2) + (size_t)(cb ^ ((r & 7) << 4)) + (size_t)tt * 128;
      __builtin_amdgcn_global_load_lds(
          (const GLOBAL_AS void*)(bg + soff),
          (LDS_AS void*)(lb + chunk * 1024),
          16, 0, 0);
    }
  };

  f32x4 acc[4][2] = {};

  loadA(0);
  gldB(0, 0);
  writeA(0);
  __syncthreads();
  loadA(1);

  int cur = 0;
  for (int tt = 0; tt < NTK; ++tt) {
    if (tt + 1 < NTK) {
      gldB(cur ^ 1, tt + 1);                 // async direct-to-LDS prefetch
      writeA(cur ^ 1);                       // regs from loadA(tt+1)
      if (tt + 2 < NTK) loadA(tt + 2);
    }
    const char* baseA = reinterpret_cast<const char*>(ldsA[cur]);
    const char* baseB = reinterpret_cast<const char*>(ldsB[cur]);
#pragma unroll
    for (int kk = 0; kk < 2; ++kk) {
      int kb = kk * 64 + (lane >> 4) * 16;
      bf16x8 af[4], bfr[2];
#pragma unroll
      for (int m = 0; m < 4; ++m) {
        int row = wm * 64 + m * 16 + (lane & 15);
        af[m] = *reinterpret_cast<const bf16x8*>(baseA + swz(row, kb));
      }
#pragma unroll
      for (int n = 0; n < 2; ++n) {
        int row = wn * 32 + n * 16 + (lane & 15);
        bfr[n] = *reinterpret_cast<const bf16x8*>(baseB + swz(row, kb));
      }
#pragma unroll
      for (int m = 0; m < 4; ++m)
#pragma unroll
        for (int n = 0; n < 2; ++n)
          acc[m][n] = __builtin_amdgcn_mfma_f32_16x16x32_bf16(af[m], bfr[n], acc[m][n], 0, 0, 0);
    }
    __syncthreads();
    cur ^= 1;
  }

  // store fp32 partial.  C layout: col=lane&15, row=(lane>>4)*4+jj
#pragma unroll
  for (int m = 0; m < 4; ++m) {
    int row0 = m_base + wm * 64 + m * 16 + (lane >> 4) * 4;
#pragma unroll
    for (int n = 0; n < 2; ++n) {
      int col = n_base + wn * 32 + n * 16 + (lane & 15);
#pragma unroll
      for (int jj = 0; jj < 4; ++jj)
        pout[(size_t)(row0 + jj) * HID + col] = acc[m][n][jj];
    }
  }
}

// ---------------- kernel 2: out = tanh(p0+p1) @ V^T + b ----------------
__device__ inline float tanh_fast(float s) {
  float e = __expf(-2.f * fabsf(s));
  float t = (1.f - e) / (1.f + e);
  return copysignf(t, s);
}

__global__ __launch_bounds__(256)
void proj_kernel(const float* __restrict__ p0, const float* __restrict__ p1,
                 const float* __restrict__ V, const float* __restrict__ bias,
                 float* __restrict__ out) {
  __shared__ float Vs[NC * HID];  // 32 KB
  int t = threadIdx.x;
#pragma unroll
  for (int p = 0; p < 8; ++p) {   // 2048 f4 / 256 threads
    int g = t + p * 256;
    reinterpret_cast<f32x4*>(Vs)[g] = reinterpret_cast<const f32x4*>(V)[g];
  }
  __syncthreads();
  int wid = t >> 6, lane = t & 63;
  int brow = blockIdx.x * 4 + wid;
  const float* r0 = p0 + (size_t)brow * HID;
  const float* r1 = p1 + (size_t)brow * HID;
  float hv[8];
#pragma unroll
  for (int jj = 0; jj < 8; ++jj) {
    float s = r0[jj * 64 + lane] + r1[jj * 64 + lane];  // coalesced
    hv[jj] = tanh_fast(s);
  }
  float acc[NC];
#pragma unroll
  for (int c = 0; c < NC; ++c) acc[c] = 0.f;
#pragma unroll
  for (int jj = 0; jj < 8; ++jj)
#pragma unroll
    for (int c = 0; c < NC; ++c)
      acc[c] += hv[jj] * Vs[c * HID + jj * 64 + lane];  // conflict-free
  float myval = 0.f;
#pragma unroll
  for (int c = 0; c < NC; ++c) {
    float s = acc[c];
#pragma unroll
    for (int off = 32; off > 0; off >>= 1) s += __shfl_xor(s, off);
    if (lane == c) myval = s;
  }
  if (lane < NC) out[(size_t)brow * NC + lane] = myval + bias[lane];
}

extern "C" void kernel_launch(void* const* d_in, const int* in_sizes, int n_in,
                              void* d_out, int out_size, void* d_ws, size_t ws_size,
                              hipStream_t stream) {
  const float* x = (const float*)d_in[0];
  const float* W = (const float*)d_in[1];
  const float* V = (const float*)d_in[2];
  const float* b = (const float*)d_in[3];
  float* out = (float*)d_out;

  ushort* Wt   = (ushort*)d_ws;                                  // 8 MB
  float*  part = (float*)((char*)d_ws + (size_t)HID * KK * 2);   // 2 x 16 MB fp32 partials
  float*  p0 = part;
  float*  p1 = part + (size_t)B * HID;

  wconv_kernel<<<HID * K / 256, 256, 0, stream>>>(W, Wt);
  gemm_splitk_kernel<<<(B / BM) * (HID / BN) * KSPLIT, 512, 0, stream>>>(x, Wt, part);
  proj_kernel<<<B / 4, 256, 0, stream>>>(p0, p1, V, b, out);
}